// Round 1
// baseline (383.034 us; speedup 1.0000x reference)
//
#include <hip/hip_runtime.h>
#include <stdint.h>

#define NTOK 4096
#define NH 12
#define HDIM 64
#define DMODEL 768
#define D3 2304

typedef __attribute__((ext_vector_type(8))) __bf16 bf16x8;
typedef __attribute__((ext_vector_type(4))) float f32x4;

#define MFMA(a, b, c) __builtin_amdgcn_mfma_f32_16x16x32_bf16((a), (b), (c), 0, 0, 0)

__device__ __forceinline__ uint16_t f2bf(float f) {
  uint32_t u = __builtin_bit_cast(uint32_t, f);
  u += 0x7fffu + ((u >> 16) & 1u);
  return (uint16_t)(u >> 16);
}
__device__ __forceinline__ uint32_t packbf2(float a, float b) {
  return (uint32_t)f2bf(a) | ((uint32_t)f2bf(b) << 16);
}

// ---------------- cast hidden fp32 -> bf16 ----------------
__global__ void va_cast_bf16(const float* __restrict__ in, uint16_t* __restrict__ out, int n4) {
  int i = blockIdx.x * 256 + threadIdx.x;
  if (i >= n4) return;
  float4 v = ((const float4*)in)[i];
  uint2 o = make_uint2(packbf2(v.x, v.y), packbf2(v.z, v.w));
  ((uint2*)out)[i] = o;
}

// ---------------- transpose + cast: W[K][N] fp32 -> Wt[N][K] bf16 ----------------
__global__ void va_transpose_cast(const float* __restrict__ W, uint16_t* __restrict__ Wt,
                                  int K, int Ncols) {
  __shared__ uint16_t tile[32][36];
  const int t = threadIdx.x;
  const int k0 = blockIdx.y * 32, n0 = blockIdx.x * 32;
  {
    int i = t >> 3, j = (t & 7) * 4;
    float4 v = *(const float4*)(W + (size_t)(k0 + i) * Ncols + n0 + j);
    tile[i][j + 0] = f2bf(v.x);
    tile[i][j + 1] = f2bf(v.y);
    tile[i][j + 2] = f2bf(v.z);
    tile[i][j + 3] = f2bf(v.w);
  }
  __syncthreads();
  {
    int c = t >> 3, kk = (t & 7) * 4;
    uint32_t lo = (uint32_t)tile[kk + 0][c] | ((uint32_t)tile[kk + 1][c] << 16);
    uint32_t hi = (uint32_t)tile[kk + 2][c] | ((uint32_t)tile[kk + 3][c] << 16);
    *(uint2*)(Wt + (size_t)(n0 + c) * K + k0 + kk) = make_uint2(lo, hi);
  }
}

// ---------------- GEMM: C[M][Nc] = A[M][K](bf16) @ Bt[Nc][K](bf16)^T + bias ----------------
// 128x128 tile, BK=32, 4 waves each 64x64, 16x16x32 MFMA. LDS pitch 40 (conflict-min).
__global__ __launch_bounds__(256) void va_gemm_bt_bias(
    const uint16_t* __restrict__ A, const uint16_t* __restrict__ Bt,
    const float* __restrict__ bias, float* __restrict__ C, int M, int Nc, int K) {
  __shared__ uint16_t As[128 * 40];
  __shared__ uint16_t Bs[128 * 40];
  const int t = threadIdx.x;
  const int w = t >> 6, ln = t & 63, quad = ln >> 4, l15 = ln & 15;
  const int m0 = blockIdx.y * 128, n0 = blockIdx.x * 128;
  const int wm = (w & 1) * 64, wn = (w >> 1) * 64;
  const int r = t >> 2, ch = t & 3;
  f32x4 acc[4][4] = {};
  const int kIters = K >> 5;
  for (int kt = 0; kt < kIters; ++kt) {
    const int kk = kt * 32;
#pragma unroll
    for (int p = 0; p < 2; ++p) {
      int row = r + p * 64;
      bf16x8 av = *(const bf16x8*)(A + (size_t)(m0 + row) * K + kk + ch * 8);
      bf16x8 bv = *(const bf16x8*)(Bt + (size_t)(n0 + row) * K + kk + ch * 8);
      *(bf16x8*)(As + row * 40 + ch * 8) = av;
      *(bf16x8*)(Bs + row * 40 + ch * 8) = bv;
    }
    __syncthreads();
    bf16x8 af[4], bfr[4];
#pragma unroll
    for (int i = 0; i < 4; ++i) {
      af[i] = *(const bf16x8*)(As + (wm + i * 16 + l15) * 40 + quad * 8);
      bfr[i] = *(const bf16x8*)(Bs + (wn + i * 16 + l15) * 40 + quad * 8);
    }
#pragma unroll
    for (int i = 0; i < 4; ++i)
#pragma unroll
      for (int j = 0; j < 4; ++j) acc[i][j] = MFMA(af[i], bfr[j], acc[i][j]);
    __syncthreads();
  }
#pragma unroll
  for (int i = 0; i < 4; ++i) {
    int row = m0 + wm + i * 16 + quad * 4;
#pragma unroll
    for (int j = 0; j < 4; ++j) {
      int col = n0 + wn + j * 16 + l15;
      float b = bias[col];
#pragma unroll
      for (int rg = 0; rg < 4; ++rg) C[(size_t)(row + rg) * Nc + col] = acc[i][j][rg] + b;
    }
  }
}

// ---------------- RoPE + layout split ----------------
// qkv fp32 [N][2304] -> Q[h][n][64] (scaled by SCALE*log2e), K[h][n][64], Vt[h][64][n], all bf16
__global__ void va_rope_split(const float* __restrict__ qkv, const float* __restrict__ cosb,
                              const float* __restrict__ sinb, uint16_t* __restrict__ Qg,
                              uint16_t* __restrict__ Kg, uint16_t* __restrict__ Vtg) {
  const int h = blockIdx.y;
  const int n = blockIdx.x * 256 + threadIdx.x;
  const float* base = qkv + (size_t)n * D3 + h * HDIM;
  const float* cr = cosb + (size_t)n * HDIM;
  const float* sr = sinb + (size_t)n * HDIM;
  const float QS = 0.125f * 1.4426950408889634f;  // SCALE * log2(e)
  uint16_t* qo = Qg + ((size_t)h * NTOK + n) * HDIM;
  uint16_t* ko = Kg + ((size_t)h * NTOK + n) * HDIM;
#pragma unroll
  for (int mtx = 0; mtx < 2; ++mtx) {
    const float* src = base + mtx * DMODEL;
    uint16_t* dst = mtx ? ko : qo;
    const float sc = mtx ? 1.0f : QS;
#pragma unroll
    for (int d4 = 0; d4 < 8; ++d4) {
      int d = d4 * 4;
      float a[4], b[4], ca[4], sa[4], cb[4], sb[4], oa[4], ob[4];
      *(float4*)a = *(const float4*)(src + d);
      *(float4*)b = *(const float4*)(src + d + 32);
      *(float4*)ca = *(const float4*)(cr + d);
      *(float4*)sa = *(const float4*)(sr + d);
      *(float4*)cb = *(const float4*)(cr + d + 32);
      *(float4*)sb = *(const float4*)(sr + d + 32);
#pragma unroll
      for (int e = 0; e < 4; ++e) {
        oa[e] = (a[e] * ca[e] - b[e] * sa[e]) * sc;  // d<32: rot = -x[d+32]
        ob[e] = (b[e] * cb[e] + a[e] * sb[e]) * sc;  // d>=32: rot = +x[d-32]
      }
      *(uint2*)(dst + d) = make_uint2(packbf2(oa[0], oa[1]), packbf2(oa[2], oa[3]));
      *(uint2*)(dst + d + 32) = make_uint2(packbf2(ob[0], ob[1]), packbf2(ob[2], ob[3]));
    }
  }
  // V transpose write: Vt[h][d][n]
#pragma unroll
  for (int d4 = 0; d4 < 16; ++d4) {
    float4 v = *(const float4*)(base + 2 * DMODEL + d4 * 4);
    int d = d4 * 4;
    size_t o = ((size_t)h * HDIM + d) * NTOK + n;
    Vtg[o] = f2bf(v.x);
    Vtg[o + NTOK] = f2bf(v.y);
    Vtg[o + 2 * NTOK] = f2bf(v.z);
    Vtg[o + 3 * NTOK] = f2bf(v.w);
  }
}

// ---------------- Flash attention ----------------
// Computes S^T = K @ Q^T (rows=keys, cols=queries) so P^T hits B-operand layout via
// packed LDS writes; O^T = V^T @ P^T. Online softmax in exp2 domain (Q pre-scaled).
// WG: 4 waves x 32 queries = 128 queries; key tiles of 32; 128 iterations.
__global__ __launch_bounds__(256) void va_flash(const uint16_t* __restrict__ Qg,
                                                const uint16_t* __restrict__ Kg,
                                                const uint16_t* __restrict__ Vtg,
                                                uint16_t* __restrict__ Og) {
  __shared__ uint16_t Ks[32 * 72];       // [key][64d], pitch 72
  __shared__ uint16_t Vts[64 * 40];      // [d][32key], pitch 40
  __shared__ uint16_t Ps[4 * 32 * 40];   // per wave: [32q][32key], pitch 40
  __shared__ uint16_t Obuf[4 * 32 * 72]; // [128q][64d], pitch 72
  const int t = threadIdx.x;
  const int w = t >> 6, ln = t & 63, quad = ln >> 4, l15 = ln & 15;
  const int h = blockIdx.y;
  const int q0 = blockIdx.x * 128;

  bf16x8 qf[2][2];
#pragma unroll
  for (int s = 0; s < 2; ++s)
#pragma unroll
    for (int ks = 0; ks < 2; ++ks)
      qf[s][ks] = *(const bf16x8*)(Qg + ((size_t)h * NTOK + q0 + w * 32 + s * 16 + l15) * HDIM +
                                   ks * 32 + quad * 8);
  f32x4 o[2][4] = {};
  float mI[2] = {-3.0e38f, -3.0e38f};
  float lI[2] = {0.f, 0.f};
  const int kr = t >> 3, kc = t & 7;  // K stage: 32 rows x 8 chunks
  const int vr = t >> 2, vc = t & 3;  // Vt stage: 64 rows x 4 chunks
  uint16_t* PsW = Ps + w * (32 * 40);

  for (int kt = 0; kt < NTOK / 32; ++kt) {
    const int key0 = kt * 32;
    bf16x8 kv = *(const bf16x8*)(Kg + ((size_t)h * NTOK + key0 + kr) * HDIM + kc * 8);
    bf16x8 vv = *(const bf16x8*)(Vtg + ((size_t)h * HDIM + vr) * NTOK + key0 + vc * 8);
    *(bf16x8*)(Ks + kr * 72 + kc * 8) = kv;
    *(bf16x8*)(Vts + vr * 40 + vc * 8) = vv;
    __syncthreads();
    bf16x8 ka[2][2], vf[4];
#pragma unroll
    for (int mt = 0; mt < 2; ++mt)
#pragma unroll
      for (int ks = 0; ks < 2; ++ks)
        ka[mt][ks] = *(const bf16x8*)(Ks + (mt * 16 + l15) * 72 + ks * 32 + quad * 8);
#pragma unroll
    for (int f = 0; f < 4; ++f) vf[f] = *(const bf16x8*)(Vts + (f * 16 + l15) * 40 + quad * 8);
#pragma unroll
    for (int s = 0; s < 2; ++s) {
      f32x4 s0 = {}, s1 = {};
      s0 = MFMA(ka[0][0], qf[s][0], s0);
      s0 = MFMA(ka[0][1], qf[s][1], s0);
      s1 = MFMA(ka[1][0], qf[s][0], s1);
      s1 = MFMA(ka[1][1], qf[s][1], s1);
      // column (=query) max over 32 keys
      float vm = fmaxf(fmaxf(fmaxf(s0[0], s0[1]), fmaxf(s0[2], s0[3])),
                       fmaxf(fmaxf(s1[0], s1[1]), fmaxf(s1[2], s1[3])));
      vm = fmaxf(vm, __shfl_xor(vm, 16, 64));
      vm = fmaxf(vm, __shfl_xor(vm, 32, 64));
      float mnew = fmaxf(mI[s], vm);
      float alpha = exp2f(mI[s] - mnew);
      mI[s] = mnew;
      float p[8];
#pragma unroll
      for (int e = 0; e < 4; ++e) p[e] = exp2f(s0[e] - mnew);
#pragma unroll
      for (int e = 0; e < 4; ++e) p[4 + e] = exp2f(s1[e] - mnew);
      float lsum = ((p[0] + p[1]) + (p[2] + p[3])) + ((p[4] + p[5]) + (p[6] + p[7]));
      lsum += __shfl_xor(lsum, 16, 64);
      lsum += __shfl_xor(lsum, 32, 64);
      lI[s] = lI[s] * alpha + lsum;
#pragma unroll
      for (int f = 0; f < 4; ++f) o[s][f] *= alpha;
      // write P^T [q][key] (packed 4 keys per b64)
      *(uint2*)(PsW + (s * 16 + l15) * 40 + quad * 4) =
          make_uint2(packbf2(p[0], p[1]), packbf2(p[2], p[3]));
      *(uint2*)(PsW + (s * 16 + l15) * 40 + 16 + quad * 4) =
          make_uint2(packbf2(p[4], p[5]), packbf2(p[6], p[7]));
      __builtin_amdgcn_sched_barrier(0);  // keep DS write->read order (intra-wave exchange)
      bf16x8 pf = *(const bf16x8*)(PsW + (s * 16 + l15) * 40 + quad * 8);
#pragma unroll
      for (int f = 0; f < 4; ++f) o[s][f] = MFMA(vf[f], pf, o[s][f]);
    }
    __syncthreads();
  }
  // epilogue: normalize, transpose via LDS, coalesced store to Og[n][h*64+d]
#pragma unroll
  for (int s = 0; s < 2; ++s) {
    float inv = 1.0f / lI[s];
#pragma unroll
    for (int f = 0; f < 4; ++f) {
      uint32_t d0 = packbf2(o[s][f][0] * inv, o[s][f][1] * inv);
      uint32_t d1 = packbf2(o[s][f][2] * inv, o[s][f][3] * inv);
      *(uint2*)(Obuf + (w * 32 + s * 16 + l15) * 72 + f * 16 + quad * 4) = make_uint2(d0, d1);
    }
  }
  __syncthreads();
#pragma unroll
  for (int rr = 0; rr < 2; ++rr) {
    int row = w * 32 + rr * 16 + (ln >> 2);
    int chunk = ln & 3;
    const uint16_t* src = Obuf + row * 72 + chunk * 16;
    uint4 a = *(const uint4*)src;
    uint4 b = *(const uint4*)(src + 8);
    uint16_t* dst = Og + (size_t)(q0 + row) * DMODEL + h * HDIM + chunk * 16;
    *(uint4*)dst = a;
    *(uint4*)(dst + 8) = b;
  }
}

extern "C" void kernel_launch(void* const* d_in, const int* in_sizes, int n_in, void* d_out,
                              int out_size, void* d_ws, size_t ws_size, hipStream_t stream) {
  (void)in_sizes; (void)n_in; (void)out_size; (void)ws_size;
  const float* hidden = (const float*)d_in[0];
  const float* cosb = (const float*)d_in[1];
  const float* sinb = (const float*)d_in[2];
  const float* qkv_w = (const float*)d_in[3];
  const float* qkv_b = (const float*)d_in[4];
  const float* proj_w = (const float*)d_in[5];
  const float* proj_b = (const float*)d_in[6];
  float* out = (float*)d_out;

  char* ws = (char*)d_ws;
  size_t off = 0;
  auto alloc = [&](size_t bytes) {
    void* p = ws + off;
    off += (bytes + 255) & ~(size_t)255;
    return p;
  };
  uint16_t* Abf = (uint16_t*)alloc((size_t)NTOK * DMODEL * 2);
  uint16_t* Wqt = (uint16_t*)alloc((size_t)D3 * DMODEL * 2);
  uint16_t* Wpt = (uint16_t*)alloc((size_t)DMODEL * DMODEL * 2);
  float* qkv = (float*)alloc((size_t)NTOK * D3 * 4);
  uint16_t* Qb = (uint16_t*)alloc((size_t)NH * NTOK * HDIM * 2);
  uint16_t* Kb = (uint16_t*)alloc((size_t)NH * NTOK * HDIM * 2);
  uint16_t* Vtb = (uint16_t*)alloc((size_t)NH * NTOK * HDIM * 2);
  uint16_t* Ob = (uint16_t*)alloc((size_t)NTOK * DMODEL * 2);
  // total ws use ~74 MB

  va_cast_bf16<<<(NTOK * DMODEL / 4 + 255) / 256, 256, 0, stream>>>(hidden, Abf,
                                                                    NTOK * DMODEL / 4);
  va_transpose_cast<<<dim3(D3 / 32, DMODEL / 32), 256, 0, stream>>>(qkv_w, Wqt, DMODEL, D3);
  va_transpose_cast<<<dim3(DMODEL / 32, DMODEL / 32), 256, 0, stream>>>(proj_w, Wpt, DMODEL,
                                                                        DMODEL);
  va_gemm_bt_bias<<<dim3(D3 / 128, NTOK / 128), 256, 0, stream>>>(Abf, Wqt, qkv_b, qkv, NTOK, D3,
                                                                  DMODEL);
  va_rope_split<<<dim3(NTOK / 256, NH), 256, 0, stream>>>(qkv, cosb, sinb, Qb, Kb, Vtb);
  va_flash<<<dim3(NTOK / 128, NH), 256, 0, stream>>>(Qb, Kb, Vtb, Ob);
  va_gemm_bt_bias<<<dim3(DMODEL / 128, NTOK / 128), 256, 0, stream>>>(Ob, Wpt, proj_b, out, NTOK,
                                                                      DMODEL, DMODEL);
}

// Round 2
// 301.354 us; speedup vs baseline: 1.2710x; 1.2710x over previous
//
#include <hip/hip_runtime.h>
#include <stdint.h>

#define NTOK 4096
#define NH 12
#define HDIM 64
#define DMODEL 768
#define D3 2304

typedef __attribute__((ext_vector_type(8))) __bf16 bf16x8;
typedef __attribute__((ext_vector_type(4))) float f32x4;

#define MFMA(a, b, c) __builtin_amdgcn_mfma_f32_16x16x32_bf16((a), (b), (c), 0, 0, 0)

__device__ __forceinline__ uint16_t f2bf(float f) {
  uint32_t u = __builtin_bit_cast(uint32_t, f);
  u += 0x7fffu + ((u >> 16) & 1u);
  return (uint16_t)(u >> 16);
}
__device__ __forceinline__ uint32_t packbf2(float a, float b) {
  return (uint32_t)f2bf(a) | ((uint32_t)f2bf(b) << 16);
}

// ---------------- cast hidden fp32 -> bf16 ----------------
__global__ void va_cast_bf16(const float* __restrict__ in, uint16_t* __restrict__ out, int n4) {
  int i = blockIdx.x * 256 + threadIdx.x;
  if (i >= n4) return;
  float4 v = ((const float4*)in)[i];
  uint2 o = make_uint2(packbf2(v.x, v.y), packbf2(v.z, v.w));
  ((uint2*)out)[i] = o;
}

// ---------------- transpose + cast: W[K][N] fp32 -> Wt[N][K] bf16 ----------------
__global__ void va_transpose_cast(const float* __restrict__ W, uint16_t* __restrict__ Wt,
                                  int K, int Ncols) {
  __shared__ uint16_t tile[32][36];
  const int t = threadIdx.x;
  const int k0 = blockIdx.y * 32, n0 = blockIdx.x * 32;
  {
    int i = t >> 3, j = (t & 7) * 4;
    float4 v = *(const float4*)(W + (size_t)(k0 + i) * Ncols + n0 + j);
    tile[i][j + 0] = f2bf(v.x);
    tile[i][j + 1] = f2bf(v.y);
    tile[i][j + 2] = f2bf(v.z);
    tile[i][j + 3] = f2bf(v.w);
  }
  __syncthreads();
  {
    int c = t >> 3, kk = (t & 7) * 4;
    uint32_t lo = (uint32_t)tile[kk + 0][c] | ((uint32_t)tile[kk + 1][c] << 16);
    uint32_t hi = (uint32_t)tile[kk + 2][c] | ((uint32_t)tile[kk + 3][c] << 16);
    *(uint2*)(Wt + (size_t)(n0 + c) * K + k0 + kk) = make_uint2(lo, hi);
  }
}

// ---------------- GEMM: C[M][Nc] = A[M][K](bf16) @ Bt[Nc][K](bf16)^T + bias ----------------
__global__ __launch_bounds__(256) void va_gemm_bt_bias(
    const uint16_t* __restrict__ A, const uint16_t* __restrict__ Bt,
    const float* __restrict__ bias, float* __restrict__ C, int M, int Nc, int K) {
  __shared__ uint16_t As[128 * 40];
  __shared__ uint16_t Bs[128 * 40];
  const int t = threadIdx.x;
  const int w = t >> 6, ln = t & 63, quad = ln >> 4, l15 = ln & 15;
  const int m0 = blockIdx.y * 128, n0 = blockIdx.x * 128;
  const int wm = (w & 1) * 64, wn = (w >> 1) * 64;
  const int r = t >> 2, ch = t & 3;
  f32x4 acc[4][4] = {};
  const int kIters = K >> 5;
  for (int kt = 0; kt < kIters; ++kt) {
    const int kk = kt * 32;
#pragma unroll
    for (int p = 0; p < 2; ++p) {
      int row = r + p * 64;
      bf16x8 av = *(const bf16x8*)(A + (size_t)(m0 + row) * K + kk + ch * 8);
      bf16x8 bv = *(const bf16x8*)(Bt + (size_t)(n0 + row) * K + kk + ch * 8);
      *(bf16x8*)(As + row * 40 + ch * 8) = av;
      *(bf16x8*)(Bs + row * 40 + ch * 8) = bv;
    }
    __syncthreads();
    bf16x8 af[4], bfr[4];
#pragma unroll
    for (int i = 0; i < 4; ++i) {
      af[i] = *(const bf16x8*)(As + (wm + i * 16 + l15) * 40 + quad * 8);
      bfr[i] = *(const bf16x8*)(Bs + (wn + i * 16 + l15) * 40 + quad * 8);
    }
#pragma unroll
    for (int i = 0; i < 4; ++i)
#pragma unroll
      for (int j = 0; j < 4; ++j) acc[i][j] = MFMA(af[i], bfr[j], acc[i][j]);
    __syncthreads();
  }
#pragma unroll
  for (int i = 0; i < 4; ++i) {
    int row = m0 + wm + i * 16 + quad * 4;
#pragma unroll
    for (int j = 0; j < 4; ++j) {
      int col = n0 + wn + j * 16 + l15;
      float b = bias[col];
#pragma unroll
      for (int rg = 0; rg < 4; ++rg) C[(size_t)(row + rg) * Nc + col] = acc[i][j][rg] + b;
    }
  }
}

// ---------------- RoPE + layout split ----------------
__global__ void va_rope_split(const float* __restrict__ qkv, const float* __restrict__ cosb,
                              const float* __restrict__ sinb, uint16_t* __restrict__ Qg,
                              uint16_t* __restrict__ Kg, uint16_t* __restrict__ Vtg) {
  const int h = blockIdx.y;
  const int n = blockIdx.x * 256 + threadIdx.x;
  const float* base = qkv + (size_t)n * D3 + h * HDIM;
  const float* cr = cosb + (size_t)n * HDIM;
  const float* sr = sinb + (size_t)n * HDIM;
  const float QS = 0.125f * 1.4426950408889634f;  // SCALE * log2(e)
  uint16_t* qo = Qg + ((size_t)h * NTOK + n) * HDIM;
  uint16_t* ko = Kg + ((size_t)h * NTOK + n) * HDIM;
#pragma unroll
  for (int mtx = 0; mtx < 2; ++mtx) {
    const float* src = base + mtx * DMODEL;
    uint16_t* dst = mtx ? ko : qo;
    const float sc = mtx ? 1.0f : QS;
#pragma unroll
    for (int d4 = 0; d4 < 8; ++d4) {
      int d = d4 * 4;
      float a[4], b[4], ca[4], sa[4], cb[4], sb[4], oa[4], ob[4];
      *(float4*)a = *(const float4*)(src + d);
      *(float4*)b = *(const float4*)(src + d + 32);
      *(float4*)ca = *(const float4*)(cr + d);
      *(float4*)sa = *(const float4*)(sr + d);
      *(float4*)cb = *(const float4*)(cr + d + 32);
      *(float4*)sb = *(const float4*)(sr + d + 32);
#pragma unroll
      for (int e = 0; e < 4; ++e) {
        oa[e] = (a[e] * ca[e] - b[e] * sa[e]) * sc;
        ob[e] = (b[e] * cb[e] + a[e] * sb[e]) * sc;
      }
      *(uint2*)(dst + d) = make_uint2(packbf2(oa[0], oa[1]), packbf2(oa[2], oa[3]));
      *(uint2*)(dst + d + 32) = make_uint2(packbf2(ob[0], ob[1]), packbf2(ob[2], ob[3]));
    }
  }
#pragma unroll
  for (int d4 = 0; d4 < 16; ++d4) {
    float4 v = *(const float4*)(base + 2 * DMODEL + d4 * 4);
    int d = d4 * 4;
    size_t o = ((size_t)h * HDIM + d) * NTOK + n;
    Vtg[o] = f2bf(v.x);
    Vtg[o + NTOK] = f2bf(v.y);
    Vtg[o + 2 * NTOK] = f2bf(v.z);
    Vtg[o + 3 * NTOK] = f2bf(v.w);
  }
}

// ---------------- Flash attention v2: 2-way key split ----------------
// Grid: x = qb(32) | ks(2), y = head. Block: 4 waves x 32q = 128 q, keys [ks*2048,+2048)
// in 32 iterations of 64-key tiles. S^T = K@Q^T; P^T via per-wave LDS (pitch-40 halves);
// O^T = V^T@P^T with V read direct from global (L2). K tile via LDS w/ register prefetch.
// Outputs unnormalized O^T (fp32) + m,l per split for the combine kernel.
__global__ __launch_bounds__(256, 4) void va_flash2(
    const uint16_t* __restrict__ Qg, const uint16_t* __restrict__ Kg,
    const uint16_t* __restrict__ Vtg, float* __restrict__ Op, float* __restrict__ Mp,
    float* __restrict__ Lp) {
  __shared__ uint16_t Ks0[64 * 40];       // K tile cols 0..31, pitch 40
  __shared__ uint16_t Ks1[64 * 40];       // K tile cols 32..63
  __shared__ uint16_t Ps[4][2][32 * 40];  // per wave, key-halves, [32q][32k] pitch 40
  const int t = threadIdx.x;
  const int w = t >> 6, ln = t & 63, quad = ln >> 4, l15 = ln & 15;
  const int h = blockIdx.y;
  const int qb = blockIdx.x & 31, ks = blockIdx.x >> 5;
  const int q0 = qb * 128;
  const int key0 = ks * 2048;

  // Q fragments: wave w handles queries q0 + w*32 + s*16 + l15
  bf16x8 qf[2][2];
#pragma unroll
  for (int s = 0; s < 2; ++s)
#pragma unroll
    for (int c = 0; c < 2; ++c)
      qf[s][c] = *(const bf16x8*)(Qg + ((size_t)h * NTOK + q0 + w * 32 + s * 16 + l15) * HDIM +
                                  c * 32 + quad * 8);
  f32x4 o[2][4] = {};
  float mI[2] = {-3.0e38f, -3.0e38f};
  float lI[2] = {0.f, 0.f};

  const int kr = t >> 2, kc = t & 3;  // staging: 64 rows x 4 chunks of 8
  const uint16_t* Kbase = Kg + ((size_t)h * NTOK + key0) * HDIM;
  bf16x8 kpre0 = *(const bf16x8*)(Kbase + (size_t)kr * HDIM + kc * 8);
  bf16x8 kpre1 = *(const bf16x8*)(Kbase + (size_t)kr * HDIM + kc * 8 + 32);

  for (int kt = 0; kt < 32; ++kt) {
    *(bf16x8*)(Ks0 + kr * 40 + kc * 8) = kpre0;
    *(bf16x8*)(Ks1 + kr * 40 + kc * 8) = kpre1;
    __syncthreads();
    if (kt + 1 < 32) {
      const uint16_t* kb = Kbase + (size_t)((kt + 1) * 64 + kr) * HDIM;
      kpre0 = *(const bf16x8*)(kb + kc * 8);
      kpre1 = *(const bf16x8*)(kb + kc * 8 + 32);
    }
    // S^T tiles: st[s][mt] covers keys mt*16+quad*4+rg, query s*16+l15
    f32x4 st[2][4];
#pragma unroll
    for (int mt = 0; mt < 4; ++mt) {
      bf16x8 ka0 = *(const bf16x8*)(Ks0 + (mt * 16 + l15) * 40 + quad * 8);
      bf16x8 ka1 = *(const bf16x8*)(Ks1 + (mt * 16 + l15) * 40 + quad * 8);
#pragma unroll
      for (int s = 0; s < 2; ++s) {
        f32x4 z = {};
        z = MFMA(ka0, qf[s][0], z);
        st[s][mt] = MFMA(ka1, qf[s][1], z);
      }
    }
    // online softmax per s-group
#pragma unroll
    for (int s = 0; s < 2; ++s) {
      float vm = st[s][0][0];
#pragma unroll
      for (int mt = 0; mt < 4; ++mt)
#pragma unroll
        for (int e = 0; e < 4; ++e) vm = fmaxf(vm, st[s][mt][e]);
      vm = fmaxf(vm, __shfl_xor(vm, 16, 64));
      vm = fmaxf(vm, __shfl_xor(vm, 32, 64));
      float mnew = fmaxf(mI[s], vm);
      float alpha = exp2f(mI[s] - mnew);
      mI[s] = mnew;
      float p[16];
#pragma unroll
      for (int mt = 0; mt < 4; ++mt)
#pragma unroll
        for (int e = 0; e < 4; ++e) p[mt * 4 + e] = exp2f(st[s][mt][e] - mnew);
      float lsum = 0.f;
#pragma unroll
      for (int e = 0; e < 16; ++e) lsum += p[e];
      lsum += __shfl_xor(lsum, 16, 64);
      lsum += __shfl_xor(lsum, 32, 64);
      lI[s] = lI[s] * alpha + lsum;
#pragma unroll
      for (int dt = 0; dt < 4; ++dt) o[s][dt] *= alpha;
#pragma unroll
      for (int mt = 0; mt < 4; ++mt) {
        *(uint2*)(&Ps[w][mt >> 1][0] + (s * 16 + l15) * 40 + (mt & 1) * 16 + quad * 4) =
            make_uint2(packbf2(p[mt * 4 + 0], p[mt * 4 + 1]),
                       packbf2(p[mt * 4 + 2], p[mt * 4 + 3]));
      }
    }
    // V fragments direct from global (L2-resident)
    bf16x8 vf[4][2];
    const uint16_t* Vb = Vtg + (size_t)h * HDIM * NTOK + key0 + kt * 64;
#pragma unroll
    for (int dt = 0; dt < 4; ++dt)
#pragma unroll
      for (int kx = 0; kx < 2; ++kx)
        vf[dt][kx] = *(const bf16x8*)(Vb + (size_t)(dt * 16 + l15) * NTOK + kx * 32 + quad * 8);
    __builtin_amdgcn_sched_barrier(0);  // DS write->read order (intra-wave P exchange)
#pragma unroll
    for (int s = 0; s < 2; ++s) {
      bf16x8 pf0 = *(const bf16x8*)(&Ps[w][0][0] + (s * 16 + l15) * 40 + quad * 8);
      bf16x8 pf1 = *(const bf16x8*)(&Ps[w][1][0] + (s * 16 + l15) * 40 + quad * 8);
#pragma unroll
      for (int dt = 0; dt < 4; ++dt) {
        o[s][dt] = MFMA(vf[dt][0], pf0, o[s][dt]);
        o[s][dt] = MFMA(vf[dt][1], pf1, o[s][dt]);
      }
    }
    __syncthreads();
  }
  // store unnormalized O^T fp32: Op[(ks*12+h)*64 + d][q], plus m,l
  float* ob = Op + ((size_t)(ks * NH + h) * HDIM) * NTOK;
#pragma unroll
  for (int s = 0; s < 2; ++s) {
    int q = q0 + w * 32 + s * 16 + l15;
#pragma unroll
    for (int dt = 0; dt < 4; ++dt)
#pragma unroll
      for (int rg = 0; rg < 4; ++rg)
        ob[(size_t)(dt * 16 + quad * 4 + rg) * NTOK + q] = o[s][dt][rg];
    if (quad == 0) {
      Mp[(size_t)(ks * NH + h) * NTOK + q] = mI[s];
      Lp[(size_t)(ks * NH + h) * NTOK + q] = lI[s];
    }
  }
}

// ---------------- combine the 2 key-splits, normalize, write bf16 [n][h*64+d] ----------------
__global__ __launch_bounds__(256) void va_combine(const float* __restrict__ Op,
                                                  const float* __restrict__ Mp,
                                                  const float* __restrict__ Lp,
                                                  uint16_t* __restrict__ Ob) {
  __shared__ float sc[2][64];
  __shared__ uint16_t T[64 * 72];
  const int h = blockIdx.y;
  const int n0 = blockIdx.x * 64;
  const int t = threadIdx.x;
  if (t < 64) {
    int n = n0 + t;
    float m1 = Mp[(size_t)h * NTOK + n], m2 = Mp[(size_t)(NH + h) * NTOK + n];
    float l1 = Lp[(size_t)h * NTOK + n], l2 = Lp[(size_t)(NH + h) * NTOK + n];
    float m = fmaxf(m1, m2);
    float a1 = exp2f(m1 - m), a2 = exp2f(m2 - m);
    float inv = 1.0f / (l1 * a1 + l2 * a2);
    sc[0][t] = a1 * inv;
    sc[1][t] = a2 * inv;
  }
  __syncthreads();
  const int d = t >> 2, c = t & 3;
  const float* p1 = Op + ((size_t)h * HDIM + d) * NTOK + n0 + c * 16;
  const float* p2 = Op + ((size_t)(NH * HDIM) + (size_t)h * HDIM + d) * NTOK + n0 + c * 16;
#pragma unroll
  for (int j = 0; j < 16; j += 4) {
    float4 o1 = *(const float4*)(p1 + j);
    float4 o2 = *(const float4*)(p2 + j);
    float r0 = o1.x * sc[0][c * 16 + j + 0] + o2.x * sc[1][c * 16 + j + 0];
    float r1 = o1.y * sc[0][c * 16 + j + 1] + o2.y * sc[1][c * 16 + j + 1];
    float r2 = o1.z * sc[0][c * 16 + j + 2] + o2.z * sc[1][c * 16 + j + 2];
    float r3 = o1.w * sc[0][c * 16 + j + 3] + o2.w * sc[1][c * 16 + j + 3];
    T[(c * 16 + j + 0) * 72 + d] = f2bf(r0);
    T[(c * 16 + j + 1) * 72 + d] = f2bf(r1);
    T[(c * 16 + j + 2) * 72 + d] = f2bf(r2);
    T[(c * 16 + j + 3) * 72 + d] = f2bf(r3);
  }
  __syncthreads();
  const int row = t >> 2, ch = t & 3;
  uint4 a = *(const uint4*)(T + row * 72 + ch * 16);
  uint4 b = *(const uint4*)(T + row * 72 + ch * 16 + 8);
  uint16_t* dst = Ob + (size_t)(n0 + row) * DMODEL + h * HDIM + ch * 16;
  *(uint4*)dst = a;
  *(uint4*)(dst + 8) = b;
}

extern "C" void kernel_launch(void* const* d_in, const int* in_sizes, int n_in, void* d_out,
                              int out_size, void* d_ws, size_t ws_size, hipStream_t stream) {
  (void)in_sizes; (void)n_in; (void)out_size; (void)ws_size;
  const float* hidden = (const float*)d_in[0];
  const float* cosb = (const float*)d_in[1];
  const float* sinb = (const float*)d_in[2];
  const float* qkv_w = (const float*)d_in[3];
  const float* qkv_b = (const float*)d_in[4];
  const float* proj_w = (const float*)d_in[5];
  const float* proj_b = (const float*)d_in[6];
  float* out = (float*)d_out;

  char* ws = (char*)d_ws;
  size_t off = 0;
  auto alloc = [&](size_t bytes) {
    void* p = ws + off;
    off += (bytes + 255) & ~(size_t)255;
    return p;
  };
  uint16_t* Abf = (uint16_t*)alloc((size_t)NTOK * DMODEL * 2);
  uint16_t* Wqt = (uint16_t*)alloc((size_t)D3 * DMODEL * 2);
  uint16_t* Wpt = (uint16_t*)alloc((size_t)DMODEL * DMODEL * 2);
  float* qkv = (float*)alloc((size_t)NTOK * D3 * 4);
  uint16_t* Qb = (uint16_t*)alloc((size_t)NH * NTOK * HDIM * 2);
  uint16_t* Kb = (uint16_t*)alloc((size_t)NH * NTOK * HDIM * 2);
  uint16_t* Vtb = (uint16_t*)alloc((size_t)NH * NTOK * HDIM * 2);
  uint16_t* Ob = (uint16_t*)alloc((size_t)NTOK * DMODEL * 2);
  float* Op = (float*)alloc((size_t)2 * NH * HDIM * NTOK * 4);
  float* Mp = (float*)alloc((size_t)2 * NH * NTOK * 4);
  float* Lp = (float*)alloc((size_t)2 * NH * NTOK * 4);

  va_cast_bf16<<<(NTOK * DMODEL / 4 + 255) / 256, 256, 0, stream>>>(hidden, Abf,
                                                                    NTOK * DMODEL / 4);
  va_transpose_cast<<<dim3(D3 / 32, DMODEL / 32), 256, 0, stream>>>(qkv_w, Wqt, DMODEL, D3);
  va_transpose_cast<<<dim3(DMODEL / 32, DMODEL / 32), 256, 0, stream>>>(proj_w, Wpt, DMODEL,
                                                                        DMODEL);
  va_gemm_bt_bias<<<dim3(D3 / 128, NTOK / 128), 256, 0, stream>>>(Abf, Wqt, qkv_b, qkv, NTOK, D3,
                                                                  DMODEL);
  va_rope_split<<<dim3(NTOK / 256, NH), 256, 0, stream>>>(qkv, cosb, sinb, Qb, Kb, Vtb);
  va_flash2<<<dim3(64, NH), 256, 0, stream>>>(Qb, Kb, Vtb, Op, Mp, Lp);
  va_combine<<<dim3(NTOK / 64, NH), 256, 0, stream>>>(Op, Mp, Lp, Ob);
  va_gemm_bt_bias<<<dim3(DMODEL / 128, NTOK / 128), 256, 0, stream>>>(Ob, Wpt, proj_b, out, NTOK,
                                                                      DMODEL, DMODEL);
}